// Round 1
// baseline (5052.416 us; speedup 1.0000x reference)
//
#include <hip/hip_runtime.h>

typedef unsigned short u16;
typedef __attribute__((ext_vector_type(8))) short short8;
typedef __attribute__((ext_vector_type(4))) float f32x4;

#define NTOK 6304   // 32*197

// ---- workspace offsets (bytes) ----
#define OFF_WQKVT 0L
#define OFF_WOT   42467328L
#define OFF_W1T   56623104L
#define OFF_W2T   113246208L
#define OFF_WPT   169869312L
#define OFF_BQKV  171048960L
#define OFF_H     171159552L
#define OFF_XN    190525440L
#define OFF_QKV   200208384L
#define OFF_SC    229257216L
#define OFF_PM1   288867840L
#define OFF_VT    327599616L
#define OFF_CN    340182528L
#define OFF_T1    340280832L
#define WS_NEEDED 340379136L

__device__ __forceinline__ u16 f2bf(float x) {
  unsigned int u = __float_as_uint(x);
  u += 0x7fffu + ((u >> 16) & 1u);
  return (u16)(u >> 16);
}

__device__ __forceinline__ float gelu_f(float x) {
  return 0.5f * x * (1.0f + erff(x * 0.70710678118654752f));
}

__device__ __forceinline__ void gload_lds16(const void* g, void* l) {
  __builtin_amdgcn_global_load_lds(
      (const __attribute__((address_space(1))) unsigned int*)g,
      (__attribute__((address_space(3))) unsigned int*)l, 16, 0, 0);
}

// Stage a 128x64 bf16 tile (rows x k) into LDS, linear dest, XOR-swizzled
// global source chunks so reads can be conflict-free (G21: both-sides swizzle).
__device__ __forceinline__ void stage_tile(const u16* src, int ld,
                                           int row0, int maxrow, int k0,
                                           char* ldsbase, int t) {
  const int wbase = t & 192;  // wave*64
#pragma unroll
  for (int p = 0; p < 4; ++p) {
    int idx = p * 256 + t;      // 16B-chunk index 0..1023
    int r = idx >> 3;           // tile row 0..127
    int cl = idx & 7;           // lds chunk
    int cg = cl ^ (r & 7);      // source chunk (involution)
    int rr = row0 + r;
    rr = rr > maxrow ? maxrow : rr;
    const u16* g = src + (long)rr * ld + (k0 + cg * 8);
    char* lp = ldsbase + (long)(p * 256 + wbase) * 16;  // wave-uniform base
    gload_lds16(g, lp);
  }
}

// C[M,N](f32|bf16) = A[M,K]bf16 @ B^T[N,K]bf16 (+bias)(+res)(gelu?), batched.
// Per-operand batch offset: (z/d)*s1 + (z%d)*s2   (z = blockIdx.y)
template <bool BIAS, bool GELU, bool RES, bool OBF16, bool REMAP>
__global__ __launch_bounds__(256) void gemm_k(
    const u16* __restrict__ A, int lda, int dA, long sA1, long sA2,
    const u16* __restrict__ Bm, int ldb, int dB, long sB1, long sB2,
    void* Cv, int ldc, int dC, long sC1, long sC2,
    const float* __restrict__ bias, const float* res, int ldres,
    int M, int N, int K, int tilesM) {
  __shared__ float4 smemv[4096];  // 64KB, 16B aligned
  char* smem = (char*)smemv;

  const int z = blockIdx.y;
  A += (long)(z / dA) * sA1 + (long)(z % dA) * sA2;
  Bm += (long)(z / dB) * sB1 + (long)(z % dB) * sB2;
  const long coff = (long)(z / dC) * sC1 + (long)(z % dC) * sC2;

  const int t = threadIdx.x;
  const int tm = blockIdx.x % tilesM, tn = blockIdx.x / tilesM;
  const int m0 = tm * 128, n0 = tn * 128;
  const int l = t & 63;
  const int lr = l & 15, kb = l >> 4;
  const int wr = (t >> 7) & 1, wc = (t >> 6) & 1;

  const f32x4 zf = {0.f, 0.f, 0.f, 0.f};
  f32x4 acc[4][4];
#pragma unroll
  for (int m = 0; m < 4; ++m)
#pragma unroll
    for (int n = 0; n < 4; ++n) acc[m][n] = zf;

  const int KT = K >> 6;
  stage_tile(A, lda, m0, M - 1, 0, smem, t);
  stage_tile(Bm, ldb, n0, N - 1, 0, smem + 16384, t);
  __syncthreads();

  for (int kt = 0; kt < KT; ++kt) {
    const int cur = kt & 1;
    if (kt + 1 < KT) {
      const int nxt = cur ^ 1;
      stage_tile(A, lda, m0, M - 1, (kt + 1) * 64, smem + nxt * 32768, t);
      stage_tile(Bm, ldb, n0, N - 1, (kt + 1) * 64, smem + nxt * 32768 + 16384, t);
    }
    const char* Ab = smem + cur * 32768;
    const char* Bb = Ab + 16384;
#pragma unroll
    for (int kk = 0; kk < 2; ++kk) {
      const int cla = ((kk << 2) + kb) ^ (lr & 7);
      short8 af[4], bfv[4];
#pragma unroll
      for (int m = 0; m < 4; ++m)
        af[m] = *(const short8*)(Ab + ((wr * 64 + m * 16 + lr) * 128 + cla * 16));
#pragma unroll
      for (int n = 0; n < 4; ++n)
        bfv[n] = *(const short8*)(Bb + ((wc * 64 + n * 16 + lr) * 128 + cla * 16));
#pragma unroll
      for (int m = 0; m < 4; ++m)
#pragma unroll
        for (int n = 0; n < 4; ++n)
          acc[m][n] = __builtin_amdgcn_mfma_f32_16x16x32_bf16(af[m], bfv[n],
                                                              acc[m][n], 0, 0, 0);
    }
    __syncthreads();
  }

#pragma unroll
  for (int n = 0; n < 4; ++n) {
    const int gc = n0 + wc * 64 + n * 16 + lr;
    if (gc >= N) continue;
    const float bv = BIAS ? bias[gc] : 0.0f;
#pragma unroll
    for (int m = 0; m < 4; ++m) {
#pragma unroll
      for (int j = 0; j < 4; ++j) {
        const int gr = m0 + wr * 64 + m * 16 + kb * 4 + j;
        if (gr >= M) continue;
        float v = acc[m][n][j] + bv;
        if (RES) v += res[(long)gr * ldres + gc];
        if (GELU) v = gelu_f(v);
        long orow = gr;
        if (REMAP) orow = (long)(gr / 196) * 197 + (gr % 196) + 1;
        if (OBF16)
          ((u16*)Cv)[coff + orow * (long)ldc + gc] = f2bf(v);
        else
          ((float*)Cv)[coff + orow * (long)ldc + gc] = v;
      }
    }
  }
}

// ---- weight repack kernels ----
// Wq/Wk/Wv (L,H,D,DH) -> fused B^T layout [L][2304][768] bf16
__global__ void k_wqkv_t(const float* __restrict__ Wq, const float* __restrict__ Wk,
                         const float* __restrict__ Wv, u16* __restrict__ out) {
  long idx = (long)blockIdx.x * 256 + threadIdx.x;  // 12*2304*768
  int d = (int)(idx % 768);
  long rest = idx / 768;
  int c = (int)(rest % 2304);
  int ly = (int)(rest / 2304);
  int sel = c / 768, cc = c % 768;
  int hh = cc >> 6, dh = cc & 63;
  const float* W = sel == 0 ? Wq : (sel == 1 ? Wk : Wv);
  out[idx] = f2bf(W[(((long)ly * 12 + hh) * 768 + d) * 64 + dh]);
}

__global__ void k_bqkv(const float* __restrict__ bq, const float* __restrict__ bk,
                       const float* __restrict__ bv, float* __restrict__ out) {
  int idx = blockIdx.x * 256 + threadIdx.x;  // 12*2304
  if (idx >= 27648) return;
  int c = idx % 2304, ly = idx / 2304;
  int sel = c / 768, cc = c % 768;
  const float* b = sel == 0 ? bq : (sel == 1 ? bk : bv);
  out[idx] = b[ly * 768 + cc];
}

// f32 [R][C] -> bf16 [C][R] tiled transpose (batched over z)
__global__ void k_transpose(const float* __restrict__ in, u16* __restrict__ out,
                            int R, int C) {
  __shared__ float tile[32][33];
  long zoff = (long)blockIdx.z * R * C;
  const float* ip = in + zoff;
  u16* op = out + zoff;
  int c0 = blockIdx.x * 32, r0 = blockIdx.y * 32;
  int tx = threadIdx.x, ty = threadIdx.y;
#pragma unroll
  for (int i = 0; i < 4; ++i)
    tile[ty + i * 8][tx] = ip[(long)(r0 + ty + i * 8) * C + c0 + tx];
  __syncthreads();
#pragma unroll
  for (int i = 0; i < 4; ++i)
    op[(long)(c0 + ty + i * 8) * R + r0 + tx] = f2bf(tile[tx][ty + i * 8]);
}

// ---- activation-side kernels ----
__global__ void k_patchify(const float* __restrict__ x, u16* __restrict__ out) {
  long idx = (long)blockIdx.x * 256 + threadIdx.x;  // 6272*768
  int f = (int)(idx % 768);
  long rp = idx / 768;
  int p = (int)(rp % 196), b = (int)(rp / 196);
  int gy = p / 14, gx = p % 14;
  int c = f >> 8, rem = f & 255;
  int i = rem >> 4, j = rem & 15;
  out[idx] = f2bf(x[(((long)b * 3 + c) * 224 + gy * 16 + i) * 224 + gx * 16 + j]);
}

__global__ void k_add_pos(float* h, const float* __restrict__ cls,
                          const float* __restrict__ pos) {
  long idx = (long)blockIdx.x * 256 + threadIdx.x;  // 32*197*768
  int d = (int)(idx % 768);
  long rs = idx / 768;
  int s = (int)(rs % 197);
  if (s == 0)
    h[idx] = cls[d] + pos[d];
  else
    h[idx] += pos[(long)s * 768 + d];
}

__global__ __launch_bounds__(256) void k_ln(const float* __restrict__ in,
                                            const float* __restrict__ g,
                                            const float* __restrict__ b,
                                            u16* __restrict__ out, int rows) {
  int w = threadIdx.x >> 6, l = threadIdx.x & 63;
  int row = blockIdx.x * 4 + w;
  if (row >= rows) return;
  const float4* ip = (const float4*)(in + (long)row * 768);
  float4 v[3];
  float s = 0.f, sq = 0.f;
#pragma unroll
  for (int i = 0; i < 3; ++i) {
    v[i] = ip[i * 64 + l];
    s += v[i].x + v[i].y + v[i].z + v[i].w;
    sq += v[i].x * v[i].x + v[i].y * v[i].y + v[i].z * v[i].z + v[i].w * v[i].w;
  }
#pragma unroll
  for (int o = 1; o < 64; o <<= 1) {
    s += __shfl_xor(s, o);
    sq += __shfl_xor(sq, o);
  }
  const float m = s * (1.f / 768.f);
  const float rs = rsqrtf(sq * (1.f / 768.f) - m * m + 1e-5f);
  ushort4* op = (ushort4*)(out + (long)row * 768);
#pragma unroll
  for (int i = 0; i < 3; ++i) {
    int c4 = (i * 64 + l) * 4;
    float4 gv = *(const float4*)(g + c4);
    float4 bv = *(const float4*)(b + c4);
    ushort4 o4;
    o4.x = f2bf((v[i].x - m) * rs * gv.x + bv.x);
    o4.y = f2bf((v[i].y - m) * rs * gv.y + bv.y);
    o4.z = f2bf((v[i].z - m) * rs * gv.z + bv.z);
    o4.w = f2bf((v[i].w - m) * rs * gv.w + bv.w);
    op[i * 64 + l] = o4;
  }
}

// scores f32 [z*197+s][197] -> P bf16 [z*197+s][256] (cols>=197 zero), scale 0.125
__global__ __launch_bounds__(256) void k_softmax(const float* __restrict__ sc,
                                                 u16* __restrict__ P) {
  int w = threadIdx.x >> 6, l = threadIdx.x & 63;
  long R = (long)blockIdx.x * 4 + w;  // 384*197 rows
  const float* row = sc + R * 197;
  float vals[4];
  float mx = -1e30f;
#pragma unroll
  for (int i = 0; i < 4; ++i) {
    int c = i * 64 + l;
    vals[i] = (c < 197) ? row[c] * 0.125f : -1e30f;
    mx = fmaxf(mx, vals[i]);
  }
#pragma unroll
  for (int o = 1; o < 64; o <<= 1) mx = fmaxf(mx, __shfl_xor(mx, o));
  float s = 0.f;
#pragma unroll
  for (int i = 0; i < 4; ++i) {
    vals[i] = (vals[i] > -1e29f) ? __expf(vals[i] - mx) : 0.f;
    s += vals[i];
  }
#pragma unroll
  for (int o = 1; o < 64; o <<= 1) s += __shfl_xor(s, o);
  const float inv = 1.0f / s;
  u16* orow = P + R * 256;
#pragma unroll
  for (int i = 0; i < 4; ++i) orow[i * 64 + l] = f2bf(vals[i] * inv);
}

// V^T padded: vt[z][dh][t(256)] from qkv[(b*197+t)*2304 + 1536 + h*64 + dh]
__global__ void k_build_vt(const u16* __restrict__ qkv, u16* __restrict__ vt) {
  long idx = (long)blockIdx.x * 256 + threadIdx.x;  // 384*64*256
  int tt = (int)(idx & 255);
  long rest = idx >> 8;
  int dh = (int)(rest & 63);
  int z = (int)(rest >> 6);
  int b = z / 12, hh = z % 12;
  u16 val = 0;
  if (tt < 197) val = qkv[(long)(b * 197 + tt) * 2304 + 1536 + hh * 64 + dh];
  vt[idx] = val;
}

// ---- head (f32, tiny) ----
__global__ void k_head_ln(const float* __restrict__ h, const float* __restrict__ g,
                          const float* __restrict__ b, float* __restrict__ out) {
  const int bb = blockIdx.x, l = threadIdx.x;  // 64 threads
  const float4* ip = (const float4*)(h + (long)bb * 197 * 768);
  float4 v[3];
  float s = 0.f, sq = 0.f;
#pragma unroll
  for (int i = 0; i < 3; ++i) {
    v[i] = ip[i * 64 + l];
    s += v[i].x + v[i].y + v[i].z + v[i].w;
    sq += v[i].x * v[i].x + v[i].y * v[i].y + v[i].z * v[i].z + v[i].w * v[i].w;
  }
#pragma unroll
  for (int o = 1; o < 64; o <<= 1) {
    s += __shfl_xor(s, o);
    sq += __shfl_xor(sq, o);
  }
  const float m = s * (1.f / 768.f);
  const float rs = rsqrtf(sq * (1.f / 768.f) - m * m + 1e-5f);
  float4* op = (float4*)(out + bb * 768);
#pragma unroll
  for (int i = 0; i < 3; ++i) {
    int c4 = (i * 64 + l) * 4;
    float4 gv = *(const float4*)(g + c4);
    float4 bv = *(const float4*)(b + c4);
    float4 o4;
    o4.x = (v[i].x - m) * rs * gv.x + bv.x;
    o4.y = (v[i].y - m) * rs * gv.y + bv.y;
    o4.z = (v[i].z - m) * rs * gv.z + bv.z;
    o4.w = (v[i].w - m) * rs * gv.w + bv.w;
    op[i * 64 + l] = o4;
  }
}

__global__ void k_head_fc(const float* __restrict__ in, const float* __restrict__ W,
                          const float* __restrict__ bias, float* __restrict__ out,
                          int K, int N, int total, int apply_gelu) {
  int idx = blockIdx.x * 256 + threadIdx.x;
  if (idx >= total) return;
  int b = idx / N, c = idx % N;
  float s = bias[c];
  const float* ip = in + (long)b * K;
  for (int k = 0; k < K; ++k) s = fmaf(ip[k], W[(long)k * N + c], s);
  out[idx] = apply_gelu ? gelu_f(s) : s;
}

extern "C" void kernel_launch(void* const* d_in, const int* in_sizes, int n_in,
                              void* d_out, int out_size, void* d_ws, size_t ws_size,
                              hipStream_t stream) {
  (void)in_sizes; (void)n_in; (void)out_size;
  if ((long)ws_size < WS_NEEDED) return;  // distinctive fail: output stays zero

  const float* x = (const float*)d_in[0];
  const float* Wp = (const float*)d_in[1];
  const float* bp = (const float*)d_in[2];
  const float* cls = (const float*)d_in[3];
  const float* pos = (const float*)d_in[4];
  const float* ln1g = (const float*)d_in[5];
  const float* ln1b = (const float*)d_in[6];
  const float* Wq = (const float*)d_in[7];
  const float* bq = (const float*)d_in[8];
  const float* Wk = (const float*)d_in[9];
  const float* bk = (const float*)d_in[10];
  const float* Wv = (const float*)d_in[11];
  const float* bv = (const float*)d_in[12];
  const float* Wo = (const float*)d_in[13];
  const float* bo = (const float*)d_in[14];
  const float* ln2g = (const float*)d_in[15];
  const float* ln2b = (const float*)d_in[16];
  const float* W1 = (const float*)d_in[17];
  const float* b1 = (const float*)d_in[18];
  const float* W2 = (const float*)d_in[19];
  const float* b2 = (const float*)d_in[20];
  const float* hlng = (const float*)d_in[21];
  const float* hlnb = (const float*)d_in[22];
  const float* hW1 = (const float*)d_in[23];
  const float* hb1 = (const float*)d_in[24];
  const float* hW2 = (const float*)d_in[25];
  const float* hb2 = (const float*)d_in[26];

  char* ws = (char*)d_ws;
  u16* wqkvt = (u16*)(ws + OFF_WQKVT);
  u16* wot = (u16*)(ws + OFF_WOT);
  u16* w1t = (u16*)(ws + OFF_W1T);
  u16* w2t = (u16*)(ws + OFF_W2T);
  u16* wpt = (u16*)(ws + OFF_WPT);
  float* bqkv = (float*)(ws + OFF_BQKV);
  float* h = (float*)(ws + OFF_H);
  u16* xn = (u16*)(ws + OFF_XN);   // also reused as attention output (o)
  u16* qkv = (u16*)(ws + OFF_QKV);
  u16* pbuf = qkv;                 // patchify buffer aliases qkv region
  float* sc = (float*)(ws + OFF_SC);
  u16* P = (u16*)(ws + OFF_PM1);
  u16* m1 = P;                     // MLP intermediate aliases P (disjoint in time)
  u16* vt = (u16*)(ws + OFF_VT);
  float* cn = (float*)(ws + OFF_CN);
  float* t1 = (float*)(ws + OFF_T1);

  // ---- per-call weight repack (stateless requirement) ----
  k_wqkv_t<<<82944, 256, 0, stream>>>(Wq, Wk, Wv, wqkvt);
  k_bqkv<<<108, 256, 0, stream>>>(bq, bk, bv, bqkv);
  k_transpose<<<dim3(24, 24, 12), dim3(32, 8), 0, stream>>>(Wo, wot, 768, 768);
  k_transpose<<<dim3(96, 24, 12), dim3(32, 8), 0, stream>>>(W1, w1t, 768, 3072);
  k_transpose<<<dim3(24, 96, 12), dim3(32, 8), 0, stream>>>(W2, w2t, 3072, 768);
  k_transpose<<<dim3(24, 24, 1), dim3(32, 8), 0, stream>>>(Wp, wpt, 768, 768);

  // ---- patch embed ----
  k_patchify<<<18816, 256, 0, stream>>>(x, pbuf);
  gemm_k<true, false, false, false, true><<<dim3(49 * 6, 1), 256, 0, stream>>>(
      pbuf, 768, 1, 0, 0, wpt, 768, 1, 0, 0, h, 768, 1, 0, 0, bp, nullptr, 0,
      6272, 768, 768, 49);
  k_add_pos<<<18912, 256, 0, stream>>>(h, cls, pos);

  // ---- transformer layers ----
  for (int ly = 0; ly < 12; ++ly) {
    k_ln<<<1576, 256, 0, stream>>>(h, ln1g + ly * 768, ln1b + ly * 768, xn, NTOK);
    gemm_k<true, false, false, true, false><<<dim3(50 * 18, 1), 256, 0, stream>>>(
        xn, 768, 1, 0, 0, wqkvt + (long)ly * 2304 * 768, 768, 1, 0, 0,
        qkv, 2304, 1, 0, 0, bqkv + ly * 2304, nullptr, 0, NTOK, 2304, 768, 50);
    k_build_vt<<<24576, 256, 0, stream>>>(qkv, vt);
    // scores = q @ k^T  (batched over z = b*12+h)
    gemm_k<false, false, false, false, false><<<dim3(4, 384), 256, 0, stream>>>(
        qkv, 2304, 12, (long)197 * 2304, 64,
        qkv + 768, 2304, 12, (long)197 * 2304, 64,
        sc, 197, 1, (long)197 * 197, 0, nullptr, nullptr, 0, 197, 197, 64, 2);
    k_softmax<<<18912, 256, 0, stream>>>(sc, P);
    // o = P @ V  -> written as [b,s,h*64+dh] bf16 into xn
    gemm_k<false, false, false, true, false><<<dim3(2, 384), 256, 0, stream>>>(
        P, 256, 1, (long)197 * 256, 0,
        vt, 256, 1, (long)64 * 256, 0,
        xn, 768, 12, (long)197 * 768, 64, nullptr, nullptr, 0, 197, 64, 256, 2);
    // h = o @ Wo + bo + h
    gemm_k<true, false, true, false, false><<<dim3(50 * 6, 1), 256, 0, stream>>>(
        xn, 768, 1, 0, 0, wot + (long)ly * 768 * 768, 768, 1, 0, 0,
        h, 768, 1, 0, 0, bo + ly * 768, h, 768, NTOK, 768, 768, 50);
    k_ln<<<1576, 256, 0, stream>>>(h, ln2g + ly * 768, ln2b + ly * 768, xn, NTOK);
    gemm_k<true, true, false, true, false><<<dim3(50 * 24, 1), 256, 0, stream>>>(
        xn, 768, 1, 0, 0, w1t + (long)ly * 3072 * 768, 768, 1, 0, 0,
        m1, 3072, 1, 0, 0, b1 + ly * 3072, nullptr, 0, NTOK, 3072, 768, 50);
    gemm_k<true, false, true, false, false><<<dim3(50 * 6, 1), 256, 0, stream>>>(
        m1, 3072, 1, 0, 0, w2t + (long)ly * 768 * 3072, 3072, 1, 0, 0,
        h, 768, 1, 0, 0, b2 + ly * 768, h, 768, NTOK, 768, 3072, 50);
  }

  // ---- head ----
  k_head_ln<<<32, 64, 0, stream>>>(h, hlng, hlnb, cn);
  k_head_fc<<<96, 256, 0, stream>>>(cn, hW1, hb1, t1, 768, 768, 32 * 768, 1);
  k_head_fc<<<125, 256, 0, stream>>>(t1, hW2, hb2, (float*)d_out, 768, 1000,
                                     32 * 1000, 0);
}

// Round 2
// 4371.026 us; speedup vs baseline: 1.1559x; 1.1559x over previous
//
#include <hip/hip_runtime.h>

typedef unsigned short u16;
typedef __attribute__((ext_vector_type(8))) short short8;
typedef __attribute__((ext_vector_type(4))) float f32x4;

#define NTOK 6304   // 32*197

// ---- workspace offsets (bytes) ----
#define OFF_WQKVT 0L
#define OFF_WOT   42467328L
#define OFF_W1T   56623104L
#define OFF_W2T   113246208L
#define OFF_WPT   169869312L
#define OFF_BQKV  171048960L
#define OFF_H     171159552L
#define OFF_XN    190525440L
#define OFF_QKV   200208384L
#define OFF_SC    229257216L
#define OFF_PM1   288867840L
#define OFF_VT    327599616L
#define OFF_CN    340182528L
#define OFF_T1    340280832L
#define WS_NEEDED 340379136L

__device__ __forceinline__ u16 f2bf(float x) {
  unsigned int u = __float_as_uint(x);
  u += 0x7fffu + ((u >> 16) & 1u);
  return (u16)(u >> 16);
}

__device__ __forceinline__ float gelu_f(float x) {
  return 0.5f * x * (1.0f + erff(x * 0.70710678118654752f));
}

__device__ __forceinline__ void gload_lds16(const void* g, void* l) {
  __builtin_amdgcn_global_load_lds(
      (const __attribute__((address_space(1))) unsigned int*)g,
      (__attribute__((address_space(3))) unsigned int*)l, 16, 0, 0);
}

// Stage a 128x64 bf16 tile (rows x k) into LDS, linear dest, XOR-swizzled
// global source chunks so reads can be conflict-free (G21: both-sides swizzle).
__device__ __forceinline__ void stage_tile(const u16* src, int ld,
                                           int row0, int maxrow, int k0,
                                           char* ldsbase, int t) {
  const int wbase = t & 192;  // wave*64
#pragma unroll
  for (int p = 0; p < 4; ++p) {
    int idx = p * 256 + t;      // 16B-chunk index 0..1023
    int r = idx >> 3;           // tile row 0..127
    int cl = idx & 7;           // lds chunk
    int cg = cl ^ (r & 7);      // source chunk (involution)
    int rr = row0 + r;
    rr = rr > maxrow ? maxrow : rr;
    const u16* g = src + (long)rr * ld + (k0 + cg * 8);
    char* lp = ldsbase + (long)(p * 256 + wbase) * 16;  // wave-uniform base
    gload_lds16(g, lp);
  }
}

// C[M,N](f32|bf16) = A[M,K]bf16 @ B^T[N,K]bf16 (+bias)(+res)(gelu?), batched.
// Per-operand batch offset: (z/d)*s1 + (z%d)*s2   (z = blockIdx.y)
// m97 structure: 128^2 tile, BK=64, single 32KB LDS buffer, 2 barriers/K-step,
// ~3 blocks/CU for implicit wave-level overlap (m114).
template <bool BIAS, bool GELU, bool RES, bool OBF16, bool REMAP>
__global__ __launch_bounds__(256, 3) void gemm_k(
    const u16* __restrict__ A, int lda, int dA, long sA1, long sA2,
    const u16* __restrict__ Bm, int ldb, int dB, long sB1, long sB2,
    void* Cv, int ldc, int dC, long sC1, long sC2,
    const float* __restrict__ bias, const float* res, int ldres,
    int M, int N, int K, int tilesM) {
  __shared__ float4 smemv[2048];  // 32KB single buffer
  char* smem = (char*)smemv;

  const int z = blockIdx.y;
  A += (long)(z / dA) * sA1 + (long)(z % dA) * sA2;
  Bm += (long)(z / dB) * sB1 + (long)(z % dB) * sB2;
  const long coff = (long)(z / dC) * sC1 + (long)(z % dC) * sC2;

  const int t = threadIdx.x;
  const int tm = blockIdx.x % tilesM, tn = blockIdx.x / tilesM;
  const int m0 = tm * 128, n0 = tn * 128;
  const int l = t & 63;
  const int lr = l & 15, kb = l >> 4;
  const int wr = (t >> 7) & 1, wc = (t >> 6) & 1;

  const f32x4 zf = {0.f, 0.f, 0.f, 0.f};
  f32x4 acc[4][4];
#pragma unroll
  for (int m = 0; m < 4; ++m)
#pragma unroll
    for (int n = 0; n < 4; ++n) acc[m][n] = zf;

  const int KT = K >> 6;
  for (int kt = 0; kt < KT; ++kt) {
    stage_tile(A, lda, m0, M - 1, kt * 64, smem, t);
    stage_tile(Bm, ldb, n0, N - 1, kt * 64, smem + 16384, t);
    __syncthreads();
    const char* Ab = smem;
    const char* Bb = smem + 16384;
#pragma unroll
    for (int kk = 0; kk < 2; ++kk) {
      const int cla = ((kk << 2) + kb) ^ (lr & 7);
      short8 af[4], bfv[4];
#pragma unroll
      for (int m = 0; m < 4; ++m)
        af[m] = *(const short8*)(Ab + ((wr * 64 + m * 16 + lr) * 128 + cla * 16));
#pragma unroll
      for (int n = 0; n < 4; ++n)
        bfv[n] = *(const short8*)(Bb + ((wc * 64 + n * 16 + lr) * 128 + cla * 16));
#pragma unroll
      for (int m = 0; m < 4; ++m)
#pragma unroll
        for (int n = 0; n < 4; ++n)
          acc[m][n] = __builtin_amdgcn_mfma_f32_16x16x32_bf16(af[m], bfv[n],
                                                              acc[m][n], 0, 0, 0);
    }
    __syncthreads();
  }

#pragma unroll
  for (int n = 0; n < 4; ++n) {
    const int gc = n0 + wc * 64 + n * 16 + lr;
    if (gc >= N) continue;
    const float bv = BIAS ? bias[gc] : 0.0f;
#pragma unroll
    for (int m = 0; m < 4; ++m) {
#pragma unroll
      for (int j = 0; j < 4; ++j) {
        const int gr = m0 + wr * 64 + m * 16 + kb * 4 + j;
        if (gr >= M) continue;
        float v = acc[m][n][j] + bv;
        if (RES) v += res[(long)gr * ldres + gc];
        if (GELU) v = gelu_f(v);
        long orow = gr;
        if (REMAP) orow = (long)(gr / 196) * 197 + (gr % 196) + 1;
        if (OBF16)
          ((u16*)Cv)[coff + orow * (long)ldc + gc] = f2bf(v);
        else
          ((float*)Cv)[coff + orow * (long)ldc + gc] = v;
      }
    }
  }
}

// ---- weight repack kernels ----
// W[ly*12+hh][768(d)][64(dh)] f32 -> wqkvt[ly][sel*768+hh*64+dh][768(d)] bf16,
// 32x32 LDS-tile transpose, coalesced both sides.
__global__ void k_wt64(const float* __restrict__ W, u16* __restrict__ out,
                       int sel) {
  __shared__ float tile[32][33];
  const int z = blockIdx.z;  // 0..143 = ly*12+hh
  const int ly = z / 12, hh = z % 12;
  const float* ip = W + (long)z * 768 * 64;
  u16* op = out + (long)ly * 2304 * 768 + ((long)sel * 768 + hh * 64) * 768;
  const int c0 = blockIdx.x * 32, r0 = blockIdx.y * 32;
  const int tx = threadIdx.x, ty = threadIdx.y;
#pragma unroll
  for (int i = 0; i < 4; ++i)
    tile[ty + i * 8][tx] = ip[(long)(r0 + ty + i * 8) * 64 + c0 + tx];
  __syncthreads();
#pragma unroll
  for (int i = 0; i < 4; ++i)
    op[(long)(c0 + ty + i * 8) * 768 + r0 + tx] = f2bf(tile[tx][ty + i * 8]);
}

__global__ void k_bqkv(const float* __restrict__ bq, const float* __restrict__ bk,
                       const float* __restrict__ bv, float* __restrict__ out) {
  int idx = blockIdx.x * 256 + threadIdx.x;  // 12*2304
  if (idx >= 27648) return;
  int c = idx % 2304, ly = idx / 2304;
  int sel = c / 768, cc = c % 768;
  const float* b = sel == 0 ? bq : (sel == 1 ? bk : bv);
  out[idx] = b[ly * 768 + cc];
}

// f32 [R][C] -> bf16 [C][R] tiled transpose (batched over z)
__global__ void k_transpose(const float* __restrict__ in, u16* __restrict__ out,
                            int R, int C) {
  __shared__ float tile[32][33];
  long zoff = (long)blockIdx.z * R * C;
  const float* ip = in + zoff;
  u16* op = out + zoff;
  int c0 = blockIdx.x * 32, r0 = blockIdx.y * 32;
  int tx = threadIdx.x, ty = threadIdx.y;
#pragma unroll
  for (int i = 0; i < 4; ++i)
    tile[ty + i * 8][tx] = ip[(long)(r0 + ty + i * 8) * C + c0 + tx];
  __syncthreads();
#pragma unroll
  for (int i = 0; i < 4; ++i)
    op[(long)(c0 + ty + i * 8) * R + r0 + tx] = f2bf(tile[tx][ty + i * 8]);
}

// ---- activation-side kernels ----
__global__ void k_patchify(const float* __restrict__ x, u16* __restrict__ out) {
  long idx = (long)blockIdx.x * 256 + threadIdx.x;  // 6272*768
  int f = (int)(idx % 768);
  long rp = idx / 768;
  int p = (int)(rp % 196), b = (int)(rp / 196);
  int gy = p / 14, gx = p % 14;
  int c = f >> 8, rem = f & 255;
  int i = rem >> 4, j = rem & 15;
  out[idx] = f2bf(x[(((long)b * 3 + c) * 224 + gy * 16 + i) * 224 + gx * 16 + j]);
}

__global__ void k_add_pos(float* h, const float* __restrict__ cls,
                          const float* __restrict__ pos) {
  long idx = (long)blockIdx.x * 256 + threadIdx.x;  // 32*197*768
  int d = (int)(idx % 768);
  long rs = idx / 768;
  int s = (int)(rs % 197);
  if (s == 0)
    h[idx] = cls[d] + pos[d];
  else
    h[idx] += pos[(long)s * 768 + d];
}

__global__ __launch_bounds__(256) void k_ln(const float* __restrict__ in,
                                            const float* __restrict__ g,
                                            const float* __restrict__ b,
                                            u16* __restrict__ out, int rows) {
  int w = threadIdx.x >> 6, l = threadIdx.x & 63;
  int row = blockIdx.x * 4 + w;
  if (row >= rows) return;
  const float4* ip = (const float4*)(in + (long)row * 768);
  float4 v[3];
  float s = 0.f, sq = 0.f;
#pragma unroll
  for (int i = 0; i < 3; ++i) {
    v[i] = ip[i * 64 + l];
    s += v[i].x + v[i].y + v[i].z + v[i].w;
    sq += v[i].x * v[i].x + v[i].y * v[i].y + v[i].z * v[i].z + v[i].w * v[i].w;
  }
#pragma unroll
  for (int o = 1; o < 64; o <<= 1) {
    s += __shfl_xor(s, o);
    sq += __shfl_xor(sq, o);
  }
  const float m = s * (1.f / 768.f);
  const float rs = rsqrtf(sq * (1.f / 768.f) - m * m + 1e-5f);
  ushort4* op = (ushort4*)(out + (long)row * 768);
#pragma unroll
  for (int i = 0; i < 3; ++i) {
    int c4 = (i * 64 + l) * 4;
    float4 gv = *(const float4*)(g + c4);
    float4 bv = *(const float4*)(b + c4);
    ushort4 o4;
    o4.x = f2bf((v[i].x - m) * rs * gv.x + bv.x);
    o4.y = f2bf((v[i].y - m) * rs * gv.y + bv.y);
    o4.z = f2bf((v[i].z - m) * rs * gv.z + bv.z);
    o4.w = f2bf((v[i].w - m) * rs * gv.w + bv.w);
    op[i * 64 + l] = o4;
  }
}

// scores f32 [z*197+s][197] -> P bf16 [z*197+s][256] (cols>=197 zero), scale 0.125
__global__ __launch_bounds__(256) void k_softmax(const float* __restrict__ sc,
                                                 u16* __restrict__ P) {
  int w = threadIdx.x >> 6, l = threadIdx.x & 63;
  long R = (long)blockIdx.x * 4 + w;  // 384*197 rows
  const float* row = sc + R * 197;
  float vals[4];
  float mx = -1e30f;
#pragma unroll
  for (int i = 0; i < 4; ++i) {
    int c = i * 64 + l;
    vals[i] = (c < 197) ? row[c] * 0.125f : -1e30f;
    mx = fmaxf(mx, vals[i]);
  }
#pragma unroll
  for (int o = 1; o < 64; o <<= 1) mx = fmaxf(mx, __shfl_xor(mx, o));
  float s = 0.f;
#pragma unroll
  for (int i = 0; i < 4; ++i) {
    vals[i] = (vals[i] > -1e29f) ? __expf(vals[i] - mx) : 0.f;
    s += vals[i];
  }
#pragma unroll
  for (int o = 1; o < 64; o <<= 1) s += __shfl_xor(s, o);
  const float inv = 1.0f / s;
  u16* orow = P + R * 256;
#pragma unroll
  for (int i = 0; i < 4; ++i) orow[i * 64 + l] = f2bf(vals[i] * inv);
}

// V^T padded: vt[z][dh][t(256)] from qkv[(b*197+t)*2304 + 1536 + h*64 + dh]
__global__ void k_build_vt(const u16* __restrict__ qkv, u16* __restrict__ vt) {
  long idx = (long)blockIdx.x * 256 + threadIdx.x;  // 384*64*256
  int tt = (int)(idx & 255);
  long rest = idx >> 8;
  int dh = (int)(rest & 63);
  int z = (int)(rest >> 6);
  int b = z / 12, hh = z % 12;
  u16 val = 0;
  if (tt < 197) val = qkv[(long)(b * 197 + tt) * 2304 + 1536 + hh * 64 + dh];
  vt[idx] = val;
}

// ---- head (f32) ----
__global__ void k_head_ln(const float* __restrict__ h, const float* __restrict__ g,
                          const float* __restrict__ b, float* __restrict__ out) {
  const int bb = blockIdx.x, l = threadIdx.x;  // 64 threads
  const float4* ip = (const float4*)(h + (long)bb * 197 * 768);
  float4 v[3];
  float s = 0.f, sq = 0.f;
#pragma unroll
  for (int i = 0; i < 3; ++i) {
    v[i] = ip[i * 64 + l];
    s += v[i].x + v[i].y + v[i].z + v[i].w;
    sq += v[i].x * v[i].x + v[i].y * v[i].y + v[i].z * v[i].z + v[i].w * v[i].w;
  }
#pragma unroll
  for (int o = 1; o < 64; o <<= 1) {
    s += __shfl_xor(s, o);
    sq += __shfl_xor(sq, o);
  }
  const float m = s * (1.f / 768.f);
  const float rs = rsqrtf(sq * (1.f / 768.f) - m * m + 1e-5f);
  float4* op = (float4*)(out + bb * 768);
#pragma unroll
  for (int i = 0; i < 3; ++i) {
    int c4 = (i * 64 + l) * 4;
    float4 gv = *(const float4*)(g + c4);
    float4 bv = *(const float4*)(b + c4);
    float4 o4;
    o4.x = (v[i].x - m) * rs * gv.x + bv.x;
    o4.y = (v[i].y - m) * rs * gv.y + bv.y;
    o4.z = (v[i].z - m) * rs * gv.z + bv.z;
    o4.w = (v[i].w - m) * rs * gv.w + bv.w;
    op[i * 64 + l] = o4;
  }
}

// out[b][c0..c0+63] = in[b][:] @ W[:, c0..c0+63] + bias, 4-way K-split + LDS
// reduce. grid = (ceil(N/64), 32), block = 256 (4 waves of 64).
template <bool GELU>
__global__ __launch_bounds__(256) void k_head_gemm(
    const float* __restrict__ in, const float* __restrict__ W,
    const float* __restrict__ bias, float* __restrict__ out, int K, int N) {
  __shared__ float partial[4][64];
  const int b = blockIdx.y;
  const int cl = threadIdx.x & 63;
  const int c = blockIdx.x * 64 + cl;
  const int kp = threadIdx.x >> 6;
  const int kc = K >> 2;
  float s = 0.f;
  if (c < N) {
    const float* ip = in + (long)b * K + kp * kc;
    const float* wp = W + (long)(kp * kc) * N + c;
    for (int k = 0; k < kc; ++k) s = fmaf(ip[k], wp[(long)k * N], s);
  }
  partial[kp][cl] = s;
  __syncthreads();
  if (kp == 0 && c < N) {
    float v = partial[0][cl] + partial[1][cl] + partial[2][cl] + partial[3][cl] +
              bias[c];
    if (GELU) v = gelu_f(v);
    out[(long)b * N + c] = v;
  }
}

extern "C" void kernel_launch(void* const* d_in, const int* in_sizes, int n_in,
                              void* d_out, int out_size, void* d_ws, size_t ws_size,
                              hipStream_t stream) {
  (void)in_sizes; (void)n_in; (void)out_size;
  if ((long)ws_size < WS_NEEDED) return;  // distinctive fail: output stays zero

  const float* x = (const float*)d_in[0];
  const float* Wp = (const float*)d_in[1];
  const float* bp = (const float*)d_in[2];
  const float* cls = (const float*)d_in[3];
  const float* pos = (const float*)d_in[4];
  const float* ln1g = (const float*)d_in[5];
  const float* ln1b = (const float*)d_in[6];
  const float* Wq = (const float*)d_in[7];
  const float* bq = (const float*)d_in[8];
  const float* Wk = (const float*)d_in[9];
  const float* bk = (const float*)d_in[10];
  const float* Wv = (const float*)d_in[11];
  const float* bv = (const float*)d_in[12];
  const float* Wo = (const float*)d_in[13];
  const float* bo = (const float*)d_in[14];
  const float* ln2g = (const float*)d_in[15];
  const float* ln2b = (const float*)d_in[16];
  const float* W1 = (const float*)d_in[17];
  const float* b1 = (const float*)d_in[18];
  const float* W2 = (const float*)d_in[19];
  const float* b2 = (const float*)d_in[20];
  const float* hlng = (const float*)d_in[21];
  const float* hlnb = (const float*)d_in[22];
  const float* hW1 = (const float*)d_in[23];
  const float* hb1 = (const float*)d_in[24];
  const float* hW2 = (const float*)d_in[25];
  const float* hb2 = (const float*)d_in[26];

  char* ws = (char*)d_ws;
  u16* wqkvt = (u16*)(ws + OFF_WQKVT);
  u16* wot = (u16*)(ws + OFF_WOT);
  u16* w1t = (u16*)(ws + OFF_W1T);
  u16* w2t = (u16*)(ws + OFF_W2T);
  u16* wpt = (u16*)(ws + OFF_WPT);
  float* bqkv = (float*)(ws + OFF_BQKV);
  float* h = (float*)(ws + OFF_H);
  u16* xn = (u16*)(ws + OFF_XN);   // also reused as attention output (o)
  u16* qkv = (u16*)(ws + OFF_QKV);
  u16* pbuf = qkv;                 // patchify buffer aliases qkv region
  float* sc = (float*)(ws + OFF_SC);
  u16* P = (u16*)(ws + OFF_PM1);
  u16* m1 = P;                     // MLP intermediate aliases P (disjoint in time)
  u16* vt = (u16*)(ws + OFF_VT);
  float* cn = (float*)(ws + OFF_CN);
  float* t1 = (float*)(ws + OFF_T1);

  // ---- per-call weight repack (stateless requirement) ----
  k_wt64<<<dim3(2, 24, 144), dim3(32, 8), 0, stream>>>(Wq, wqkvt, 0);
  k_wt64<<<dim3(2, 24, 144), dim3(32, 8), 0, stream>>>(Wk, wqkvt, 1);
  k_wt64<<<dim3(2, 24, 144), dim3(32, 8), 0, stream>>>(Wv, wqkvt, 2);
  k_bqkv<<<108, 256, 0, stream>>>(bq, bk, bv, bqkv);
  k_transpose<<<dim3(24, 24, 12), dim3(32, 8), 0, stream>>>(Wo, wot, 768, 768);
  k_transpose<<<dim3(96, 24, 12), dim3(32, 8), 0, stream>>>(W1, w1t, 768, 3072);
  k_transpose<<<dim3(24, 96, 12), dim3(32, 8), 0, stream>>>(W2, w2t, 3072, 768);
  k_transpose<<<dim3(24, 24, 1), dim3(32, 8), 0, stream>>>(Wp, wpt, 768, 768);

  // ---- patch embed ----
  k_patchify<<<18816, 256, 0, stream>>>(x, pbuf);
  gemm_k<true, false, false, false, true><<<dim3(49 * 6, 1), 256, 0, stream>>>(
      pbuf, 768, 1, 0, 0, wpt, 768, 1, 0, 0, h, 768, 1, 0, 0, bp, nullptr, 0,
      6272, 768, 768, 49);
  k_add_pos<<<18912, 256, 0, stream>>>(h, cls, pos);

  // ---- transformer layers ----
  for (int ly = 0; ly < 12; ++ly) {
    k_ln<<<1576, 256, 0, stream>>>(h, ln1g + ly * 768, ln1b + ly * 768, xn, NTOK);
    gemm_k<true, false, false, true, false><<<dim3(50 * 18, 1), 256, 0, stream>>>(
        xn, 768, 1, 0, 0, wqkvt + (long)ly * 2304 * 768, 768, 1, 0, 0,
        qkv, 2304, 1, 0, 0, bqkv + ly * 2304, nullptr, 0, NTOK, 2304, 768, 50);
    k_build_vt<<<24576, 256, 0, stream>>>(qkv, vt);
    // scores = q @ k^T  (batched over z = b*12+h)
    gemm_k<false, false, false, false, false><<<dim3(4, 384), 256, 0, stream>>>(
        qkv, 2304, 12, (long)197 * 2304, 64,
        qkv + 768, 2304, 12, (long)197 * 2304, 64,
        sc, 197, 1, (long)197 * 197, 0, nullptr, nullptr, 0, 197, 197, 64, 2);
    k_softmax<<<18912, 256, 0, stream>>>(sc, P);
    // o = P @ V  -> written as [b,s,h*64+dh] bf16 into xn
    gemm_k<false, false, false, true, false><<<dim3(2, 384), 256, 0, stream>>>(
        P, 256, 1, (long)197 * 256, 0,
        vt, 256, 1, (long)64 * 256, 0,
        xn, 768, 12, (long)197 * 768, 64, nullptr, nullptr, 0, 197, 64, 256, 2);
    // h = o @ Wo + bo + h
    gemm_k<true, false, true, false, false><<<dim3(50 * 6, 1), 256, 0, stream>>>(
        xn, 768, 1, 0, 0, wot + (long)ly * 768 * 768, 768, 1, 0, 0,
        h, 768, 1, 0, 0, bo + ly * 768, h, 768, NTOK, 768, 768, 50);
    k_ln<<<1576, 256, 0, stream>>>(h, ln2g + ly * 768, ln2b + ly * 768, xn, NTOK);
    gemm_k<true, true, false, true, false><<<dim3(50 * 24, 1), 256, 0, stream>>>(
        xn, 768, 1, 0, 0, w1t + (long)ly * 3072 * 768, 768, 1, 0, 0,
        m1, 3072, 1, 0, 0, b1 + ly * 3072, nullptr, 0, NTOK, 3072, 768, 50);
    gemm_k<true, false, true, false, false><<<dim3(50 * 6, 1), 256, 0, stream>>>(
        m1, 3072, 1, 0, 0, w2t + (long)ly * 768 * 3072, 3072, 1, 0, 0,
        h, 768, 1, 0, 0, b2 + ly * 768, h, 768, NTOK, 768, 3072, 50);
  }

  // ---- head ----
  k_head_ln<<<32, 64, 0, stream>>>(h, hlng, hlnb, cn);
  k_head_gemm<true><<<dim3(12, 32), 256, 0, stream>>>(cn, hW1, hb1, t1, 768, 768);
  k_head_gemm<false><<<dim3(16, 32), 256, 0, stream>>>(t1, hW2, hb2, (float*)d_out,
                                                       768, 1000);
}